// Round 3
// baseline (273.446 us; speedup 1.0000x reference)
//
#include <hip/hip_runtime.h>

#define USER_NUM 100000
#define ITEM_NUM 50000
#define HIDDEN   64
#define BATCH    16384
#define KNB      50
#define NBLOCKS  (BATCH / 4)   // 4096, one wave per batch element, 4 waves/block

// fast, numerically stable log-sigmoid: min(x,0) - log(1 + exp(-|x|))
__device__ __forceinline__ float log_sigmoid(float x) {
    return fminf(x, 0.0f) - __logf(1.0f + __expf(-fabsf(x)));
}

__device__ __forceinline__ float dot4(float4 a, float4 b) {
    return a.x * b.x + a.y * b.y + a.z * b.z + a.w * b.w;
}

// butterfly sum over the 16-lane group (masks 1,2,4,8 stay within group)
__device__ __forceinline__ float red16(float v) {
    v += __shfl_xor(v, 1);
    v += __shfl_xor(v, 2);
    v += __shfl_xor(v, 4);
    v += __shfl_xor(v, 8);
    return v;
}

__global__ __launch_bounds__(256) void ultragcn_fused(
    const int*   __restrict__ user,
    const int*   __restrict__ pos,
    const int*   __restrict__ neg,
    const float* __restrict__ pos_beta,
    const float* __restrict__ neg_beta,
    const float* __restrict__ weights,
    const int*   __restrict__ neighbor,
    const float* __restrict__ embs,
    float*       __restrict__ partial,
    unsigned*    __restrict__ counter,
    float*       __restrict__ out)
{
    const int tid  = threadIdx.x;
    const int wave = tid >> 6;       // 0..3
    const int lane = tid & 63;
    const int i    = blockIdx.x * 4 + wave;   // batch element

    const int g  = lane >> 4;        // group 0..3 within wave
    const int gl = lane & 15;        // lane within group (one float4 of the 64-dim row)
    const unsigned goff = (unsigned)(gl << 4);   // byte offset within a 256 B row

    const int u = user[i];
    const int p = pos[i];
    const int n = neg[i];
    const int item = p - USER_NUM;

    // issue the index/weight loads first: the gathers depend on them, and their
    // latency overlaps the u/p/n row loads below
    int   nbv = 0;
    float wv  = 0.0f;
    if (lane < KNB) {
        nbv = neighbor[item * KNB + lane];
        wv  = weights[item * KNB + lane];
    }

    const char* embsb = (const char*)embs;   // rows are 256 B; table 38.4 MB -> u32 offsets

    const float4 u4 = *(const float4*)(embsb + (unsigned)u * 256u + goff);
    const float4 p4 = *(const float4*)(embsb + (unsigned)p * 256u + goff);
    const float4 n4 = *(const float4*)(embsb + (unsigned)n * 256u + goff);

    // Batch ALL neighbor gathers up front into registers: 13 independent
    // global_load_dwordx4 in flight per wave. Group g handles k = 4*t + g;
    // k>=50 broadcasts lanes 50/51 -> {row 0, weight 0} = harmless dummy.
    float4 e[13];
#pragma unroll
    for (int t = 0; t < 13; ++t) {
        const int nb = __shfl(nbv, 4 * t + g);
        e[t] = *(const float4*)(embsb + (unsigned)nb * 256u + goff);
    }
    float wk[13];
#pragma unroll
    for (int t = 0; t < 13; ++t) {
        wk[t] = __shfl(wv, 4 * t + g);
    }

    const float pos_logit = red16(dot4(u4, p4));
    const float neg_logit = red16(dot4(u4, n4));

    float li = 0.0f;
#pragma unroll
    for (int t = 0; t < 13; ++t) {
        const float d = red16(dot4(u4, e[t]));
        li += -log_sigmoid(d) * wk[t];
    }
    li += __shfl_xor(li, 16);
    li += __shfl_xor(li, 32);

    const float pb = pos_beta[i];
    const float nb = neg_beta[i];
    const float contrib = 2.5f * li
                        - (1.0f + pb) * log_sigmoid(pos_logit)
                        - (1.0f + nb) * log_sigmoid(-neg_logit);

    // ---- block partial + last-block-done reduction (deterministic order) ----
    __shared__ float s[4];
    __shared__ int   done;
    if (lane == 0) s[wave] = contrib;
    __syncthreads();
    if (tid == 0) {
        partial[blockIdx.x] = s[0] + s[1] + s[2] + s[3];
        __threadfence();   // device-scope: partial visible before counter bump
        unsigned prev = __hip_atomic_fetch_add(counter, 1u, __ATOMIC_ACQ_REL,
                                               __HIP_MEMORY_SCOPE_AGENT);
        done = (prev == (unsigned)(NBLOCKS - 1)) ? 1 : 0;
    }
    __syncthreads();

    if (done) {
        __threadfence();   // acquire side
        float v = 0.0f;
#pragma unroll
        for (int r = 0; r < NBLOCKS / 256; ++r) {
            v += __hip_atomic_load(&partial[r * 256 + tid], __ATOMIC_RELAXED,
                                   __HIP_MEMORY_SCOPE_AGENT);
        }
        v += __shfl_xor(v, 1);
        v += __shfl_xor(v, 2);
        v += __shfl_xor(v, 4);
        v += __shfl_xor(v, 8);
        v += __shfl_xor(v, 16);
        v += __shfl_xor(v, 32);
        __shared__ float ws[4];
        if (lane == 0) ws[wave] = v;
        __syncthreads();
        if (tid == 0) out[0] = ws[0] + ws[1] + ws[2] + ws[3];
    }
}

extern "C" void kernel_launch(void* const* d_in, const int* in_sizes, int n_in,
                              void* d_out, int out_size, void* d_ws, size_t ws_size,
                              hipStream_t stream)
{
    const int*   user     = (const int*)  d_in[0];
    const int*   pos      = (const int*)  d_in[1];
    const int*   neg      = (const int*)  d_in[2];
    const float* pos_beta = (const float*)d_in[3];
    const float* neg_beta = (const float*)d_in[4];
    const float* weights  = (const float*)d_in[5];
    const int*   neighbor = (const int*)  d_in[6];
    const float* embs     = (const float*)d_in[7];

    float*    partial = (float*)d_ws;                         // 4096 floats
    unsigned* counter = (unsigned*)((char*)d_ws + NBLOCKS * sizeof(float));

    hipMemsetAsync(counter, 0, sizeof(unsigned), stream);     // graph-capturable

    ultragcn_fused<<<NBLOCKS, 256, 0, stream>>>(
        user, pos, neg, pos_beta, neg_beta, weights, neighbor, embs,
        partial, counter, (float*)d_out);
}

// Round 4
// 73.469 us; speedup vs baseline: 3.7219x; 3.7219x over previous
//
#include <hip/hip_runtime.h>

#define USER_NUM 100000
#define ITEM_NUM 50000
#define HIDDEN   64
#define BATCH    16384
#define KNB      50
#define NBLOCKS  (BATCH / 4)   // 4096, one wave per batch element, 4 waves/block

// fast, numerically stable log-sigmoid: min(x,0) - log(1 + exp(-|x|))
__device__ __forceinline__ float log_sigmoid(float x) {
    return fminf(x, 0.0f) - __logf(1.0f + __expf(-fabsf(x)));
}

__device__ __forceinline__ float dot4(float4 a, float4 b) {
    return a.x * b.x + a.y * b.y + a.z * b.z + a.w * b.w;
}

// butterfly sum over the 16-lane group (masks 1,2,4,8 stay within group)
__device__ __forceinline__ float red16(float v) {
    v += __shfl_xor(v, 1);
    v += __shfl_xor(v, 2);
    v += __shfl_xor(v, 4);
    v += __shfl_xor(v, 8);
    return v;
}

__global__ __launch_bounds__(256) void ultragcn_main(
    const int*   __restrict__ user,
    const int*   __restrict__ pos,
    const int*   __restrict__ neg,
    const float* __restrict__ pos_beta,
    const float* __restrict__ neg_beta,
    const float* __restrict__ weights,
    const int*   __restrict__ neighbor,
    const float* __restrict__ embs,
    float*       __restrict__ out)
{
    const int tid  = threadIdx.x;
    const int wave = tid >> 6;       // 0..3
    const int lane = tid & 63;
    const int i    = blockIdx.x * 4 + wave;   // batch element

    const int g  = lane >> 4;        // group 0..3 within wave
    const int gl = lane & 15;        // lane within group (one float4 of the 64-dim row)
    const unsigned goff = (unsigned)(gl << 4);   // byte offset within a 256 B row

    const int u = user[i];
    const int p = pos[i];
    const int n = neg[i];
    const int item = p - USER_NUM;

    // issue index/weight loads first; their latency overlaps the row loads
    int   nbv = 0;
    float wv  = 0.0f;
    if (lane < KNB) {
        nbv = neighbor[item * KNB + lane];
        wv  = weights[item * KNB + lane];
    }

    const char* embsb = (const char*)embs;   // rows are 256 B; table 38.4 MB -> u32 offsets

    const float4 u4 = *(const float4*)(embsb + (unsigned)u * 256u + goff);
    const float4 p4 = *(const float4*)(embsb + (unsigned)p * 256u + goff);
    const float4 n4 = *(const float4*)(embsb + (unsigned)n * 256u + goff);

    // Batch ALL neighbor gathers up front: 13 independent global_load_dwordx4
    // in flight per wave. Group g handles k = 4*t + g; k>=50 broadcasts lanes
    // 50/51 -> {row 0, weight 0} = harmless dummy.
    float4 e[13];
#pragma unroll
    for (int t = 0; t < 13; ++t) {
        const int nb = __shfl(nbv, 4 * t + g);
        e[t] = *(const float4*)(embsb + (unsigned)nb * 256u + goff);
    }
    float wk[13];
#pragma unroll
    for (int t = 0; t < 13; ++t) {
        wk[t] = __shfl(wv, 4 * t + g);
    }

    const float pos_logit = red16(dot4(u4, p4));
    const float neg_logit = red16(dot4(u4, n4));

    float li = 0.0f;
#pragma unroll
    for (int t = 0; t < 13; ++t) {
        const float d = red16(dot4(u4, e[t]));
        li += -log_sigmoid(d) * wk[t];
    }
    li += __shfl_xor(li, 16);
    li += __shfl_xor(li, 32);

    const float pb = pos_beta[i];
    const float nb = neg_beta[i];
    const float contrib = 2.5f * li
                        - (1.0f + pb) * log_sigmoid(pos_logit)
                        - (1.0f + nb) * log_sigmoid(-neg_logit);

    // block partial -> ONE native f32 atomic per block (no fence, no cache
    // maintenance; routes to the coherent point). 4096 atomics spread over
    // the kernel's lifetime.
    __shared__ float s[4];
    if (lane == 0) s[wave] = contrib;
    __syncthreads();
    if (tid == 0) {
        unsafeAtomicAdd(out, s[0] + s[1] + s[2] + s[3]);
    }
}

extern "C" void kernel_launch(void* const* d_in, const int* in_sizes, int n_in,
                              void* d_out, int out_size, void* d_ws, size_t ws_size,
                              hipStream_t stream)
{
    const int*   user     = (const int*)  d_in[0];
    const int*   pos      = (const int*)  d_in[1];
    const int*   neg      = (const int*)  d_in[2];
    const float* pos_beta = (const float*)d_in[3];
    const float* neg_beta = (const float*)d_in[4];
    const float* weights  = (const float*)d_in[5];
    const int*   neighbor = (const int*)  d_in[6];
    const float* embs     = (const float*)d_in[7];

    // accumulator must start at zero every call (harness does not re-poison
    // between graph replays) — 4 B async memset is graph-capturable
    hipMemsetAsync(d_out, 0, sizeof(float), stream);

    ultragcn_main<<<NBLOCKS, 256, 0, stream>>>(
        user, pos, neg, pos_beta, neg_beta, weights, neighbor, embs,
        (float*)d_out);
}

// Round 5
// 37.551 us; speedup vs baseline: 7.2819x; 1.9565x over previous
//
#include <hip/hip_runtime.h>

#define USER_NUM 100000
#define ITEM_NUM 50000
#define HIDDEN   64
#define BATCH    16384
#define KNB      50
#define NBLOCKS  2048          // 8 blocks/CU x 256 CUs: exactly resident, G=1
#define EPW      2             // elements per wave: 2048 blk * 4 waves * 2 = 16384

// fast, numerically stable log-sigmoid: min(x,0) - log(1 + exp(-|x|))
__device__ __forceinline__ float log_sigmoid(float x) {
    return fminf(x, 0.0f) - __logf(1.0f + __expf(-fabsf(x)));
}

__device__ __forceinline__ float dot4(float4 a, float4 b) {
    return a.x * b.x + a.y * b.y + a.z * b.z + a.w * b.w;
}

// butterfly sum over the 16-lane group (masks 1,2,4,8 stay within group)
__device__ __forceinline__ float red16(float v) {
    v += __shfl_xor(v, 1);
    v += __shfl_xor(v, 2);
    v += __shfl_xor(v, 4);
    v += __shfl_xor(v, 8);
    return v;
}

__global__ __launch_bounds__(256) void ultragcn_main(
    const int*   __restrict__ user,
    const int*   __restrict__ pos,
    const int*   __restrict__ neg,
    const float* __restrict__ pos_beta,
    const float* __restrict__ neg_beta,
    const float* __restrict__ weights,
    const int*   __restrict__ neighbor,
    const float* __restrict__ embs,
    float*       __restrict__ partial)
{
    const int tid  = threadIdx.x;
    const int wave = tid >> 6;       // 0..3
    const int lane = tid & 63;
    const int wid  = blockIdx.x * 4 + wave;   // global wave id, 0..8191

    const int g  = lane >> 4;        // group 0..3 within wave
    const int gl = lane & 15;        // lane within group (one float4 of the 64-dim row)
    const unsigned goff = (unsigned)(gl << 4);   // byte offset within a 256 B row

    const char* embsb = (const char*)embs;   // rows are 256 B; table 38.4 MB -> u32 offsets

    float acc = 0.0f;   // duplicated across lanes; lane 0's value is used

    // #pragma unroll 1: keep one element's loads live at a time so VGPR stays
    // ~40 and all 8 blocks/CU (32 waves/CU) remain resident.
#pragma unroll 1
    for (int t = 0; t < EPW; ++t) {
        const int i = wid * EPW + t;

        const int u = user[i];
        const int p = pos[i];
        const int n = neg[i];
        const int item = p - USER_NUM;

        // index/weight loads first; their latency overlaps the row loads
        int   nbv = 0;
        float wv  = 0.0f;
        if (lane < KNB) {
            nbv = neighbor[item * KNB + lane];
            wv  = weights[item * KNB + lane];
        }

        const float4 u4 = *(const float4*)(embsb + (unsigned)u * 256u + goff);
        const float4 p4 = *(const float4*)(embsb + (unsigned)p * 256u + goff);
        const float4 n4 = *(const float4*)(embsb + (unsigned)n * 256u + goff);

        // Batch ALL neighbor gathers into registers: 13 independent
        // global_load_dwordx4 in flight per wave. Group g handles k = 4*q + g;
        // k>=50 broadcasts lanes 50/51 -> {row 0, weight 0} = harmless dummy.
        float4 e[13];
#pragma unroll
        for (int q = 0; q < 13; ++q) {
            const int nb = __shfl(nbv, 4 * q + g);
            e[q] = *(const float4*)(embsb + (unsigned)nb * 256u + goff);
        }
        float wk[13];
#pragma unroll
        for (int q = 0; q < 13; ++q) {
            wk[q] = __shfl(wv, 4 * q + g);
        }

        const float pos_logit = red16(dot4(u4, p4));
        const float neg_logit = red16(dot4(u4, n4));

        float li = 0.0f;
#pragma unroll
        for (int q = 0; q < 13; ++q) {
            const float d = red16(dot4(u4, e[q]));
            li += -log_sigmoid(d) * wk[q];
        }
        li += __shfl_xor(li, 16);
        li += __shfl_xor(li, 32);

        const float pb = pos_beta[i];
        const float nb = neg_beta[i];
        acc += 2.5f * li
             - (1.0f + pb) * log_sigmoid(pos_logit)
             - (1.0f + nb) * log_sigmoid(-neg_logit);
    }

    // block partial (plain store; no atomics, no fences)
    __shared__ float s[4];
    if (lane == 0) s[wave] = acc;
    __syncthreads();
    if (tid == 0) {
        partial[blockIdx.x] = s[0] + s[1] + s[2] + s[3];
    }
}

__global__ __launch_bounds__(256) void ultragcn_reduce(
    const float* __restrict__ partial, float* __restrict__ out)
{
    const int tid  = threadIdx.x;
    const int lane = tid & 63;
    const int wave = tid >> 6;

    // NBLOCKS = 2048 = 512 float4 = 256 threads x 2
    const float4* p4 = (const float4*)partial;
    float s = 0.0f;
#pragma unroll
    for (int r = 0; r < NBLOCKS / 1024; ++r) {
        float4 v = p4[r * 256 + tid];
        s += (v.x + v.y) + (v.z + v.w);
    }

    s += __shfl_xor(s, 1);
    s += __shfl_xor(s, 2);
    s += __shfl_xor(s, 4);
    s += __shfl_xor(s, 8);
    s += __shfl_xor(s, 16);
    s += __shfl_xor(s, 32);

    __shared__ float ws[4];
    if (lane == 0) ws[wave] = s;
    __syncthreads();
    if (tid == 0) out[0] = ws[0] + ws[1] + ws[2] + ws[3];
}

extern "C" void kernel_launch(void* const* d_in, const int* in_sizes, int n_in,
                              void* d_out, int out_size, void* d_ws, size_t ws_size,
                              hipStream_t stream)
{
    const int*   user     = (const int*)  d_in[0];
    const int*   pos      = (const int*)  d_in[1];
    const int*   neg      = (const int*)  d_in[2];
    const float* pos_beta = (const float*)d_in[3];
    const float* neg_beta = (const float*)d_in[4];
    const float* weights  = (const float*)d_in[5];
    const int*   neighbor = (const int*)  d_in[6];
    const float* embs     = (const float*)d_in[7];

    float* out     = (float*)d_out;
    float* partial = (float*)d_ws;       // 2048 floats = 8 KB scratch

    ultragcn_main<<<NBLOCKS, 256, 0, stream>>>(
        user, pos, neg, pos_beta, neg_beta, weights, neighbor, embs, partial);
    ultragcn_reduce<<<1, 256, 0, stream>>>(partial, out);
}